// Round 10
// baseline (198.240 us; speedup 1.0000x reference)
//
#include <hip/hip_runtime.h>
#include <hip/hip_fp16.h>
#include <cstdint>

typedef unsigned short u16;
typedef __attribute__((ext_vector_type(8))) short short8;
typedef __attribute__((ext_vector_type(4))) float float4v;

#define NTOK 8192
#define HDIM 1024
#define NEXP 8
// fat kernel (8-phase, 256x256, BK=64)
#define HTILE (128 * 64)         // one half-tile: 8192 u16 = 16 KB
#define NITF 8                   // 8 main iters x 2 K-tiles
#define MAXT256 72               // max 256-m-tiles: 64 + 8 rounding partials
#define FATT 64                  // fat kernel covers global 256-tiles [0,64) -- always valid
// thin kernel (R3 engine, 128x128, BK=32)
#define TMT 128
#define BKT 32
#define NITT (HDIM / BKT)        // 32
#define LAT (TMT * BKT)          // 4096 u16 = 8 KB
// prep
#define WBLK 2048  // W-transpose blocks (64x64 tiles x 8 experts)
#define RBLK 2048  // router blocks (4 tokens each)

__device__ __forceinline__ u16 f2bf(float f) {
    union { float f; uint32_t u; } v; v.f = f;
    uint32_t u = v.u;
    return (u16)((u + 0x7FFFu + ((u >> 16) & 1u)) >> 16);
}

// async global->LDS, 16B per lane; LDS dest = wave-uniform base + lane*16
__device__ __forceinline__ void gll16(const u16* g, u16* l) {
    __builtin_amdgcn_global_load_lds(
        (const __attribute__((address_space(1))) uint32_t*)g,
        (__attribute__((address_space(3))) uint32_t*)l,
        16, 0, 0);
}

// ---------------- fused prep: W transpose+quantize AND router AND ctrl zeroing ---------
__global__ __launch_bounds__(256) void prep(const float* __restrict__ x,
                                            const float* __restrict__ rw,
                                            const float* __restrict__ ew,
                                            u16* __restrict__ x_bf,
                                            u16* __restrict__ w_bf,
                                            float* __restrict__ wt0,
                                            float* __restrict__ wt1,
                                            float* __restrict__ biasv,
                                            int* __restrict__ sel,
                                            int* __restrict__ ctrl) {
    if (blockIdx.x == 0 && threadIdx.x < 132) ctrl[threadIdx.x] = 0;  // counts[8x16] + done

    if (blockIdx.x < WBLK) {
        __shared__ float tile[64][65];       // +1 pad, 2-way aliasing = free
        const int bid = blockIdx.x;
        const int e  = bid >> 8;                   // 8 experts x 256 tiles
        const int k0 = ((bid >> 4) & 15) * 64;
        const int n0 = (bid & 15) * 64;
        const int kr = threadIdx.x >> 2;           // 0..63
        const int ng = (threadIdx.x & 3) * 16;     // 0,16,32,48
        const float* src = ew + ((size_t)e << 20) + (size_t)(k0 + kr) * HDIM + n0 + ng;
#pragma unroll
        for (int j = 0; j < 4; j++) {
            const float4 v = *(const float4*)(src + 4 * j);
            tile[kr][ng + 4*j]     = v.x;
            tile[kr][ng + 4*j + 1] = v.y;
            tile[kr][ng + 4*j + 2] = v.z;
            tile[kr][ng + 4*j + 3] = v.w;
        }
        __syncthreads();
        const int nr = threadIdx.x >> 2;           // 0..63
        const int kg = (threadIdx.x & 3) * 16;
        u16* dst = w_bf + ((size_t)e << 20) + (size_t)(n0 + nr) * HDIM + k0 + kg;
#pragma unroll
        for (int j = 0; j < 4; j++) {
            ushort4 o;
            o.x = f2bf(tile[kg + 4*j][nr]);
            o.y = f2bf(tile[kg + 4*j + 1][nr]);
            o.z = f2bf(tile[kg + 4*j + 2][nr]);
            o.w = f2bf(tile[kg + 4*j + 3][nr]);
            *(ushort4*)(dst + 4 * j) = o;
        }
    } else {
        const int wv = threadIdx.x >> 6;
        const int l  = threadIdx.x & 63;
        const int n  = (blockIdx.x - WBLK) * 4 + wv;  // one wave per token
        const float4* xr = (const float4*)(x + (size_t)n * HDIM);
        ushort4* xo = (ushort4*)(x_bf + (size_t)n * HDIM);

        float4 xv[4];
#pragma unroll
        for (int t = 0; t < 4; t++) {
            xv[t] = xr[t * 64 + l];
            ushort4 p;
            p.x = f2bf(xv[t].x); p.y = f2bf(xv[t].y);
            p.z = f2bf(xv[t].z); p.w = f2bf(xv[t].w);
            xo[t * 64 + l] = p;
        }

        float logits[NEXP];
#pragma unroll
        for (int e = 0; e < NEXP; e++) {
            const float4* rwe = (const float4*)(rw + e * HDIM);
            float acc = 0.f;
#pragma unroll
            for (int t = 0; t < 4; t++) {
                const float4 r = rwe[t * 64 + l];
                acc += xv[t].x * r.x + xv[t].y * r.y + xv[t].z * r.z + xv[t].w * r.w;
            }
#pragma unroll
            for (int s = 32; s > 0; s >>= 1) acc += __shfl_xor(acc, s, 64);
            logits[e] = acc;
        }

        if (l == 0) {
            float mx = logits[0];
#pragma unroll
            for (int e = 1; e < NEXP; e++) mx = fmaxf(mx, logits[e]);
            float p[NEXP]; float sum = 0.f;
#pragma unroll
            for (int e = 0; e < NEXP; e++) { p[e] = expf(logits[e] - mx); sum += p[e]; }
            const float inv = 1.f / sum;
#pragma unroll
            for (int e = 0; e < NEXP; e++) p[e] *= inv;
            int e0 = 0;
#pragma unroll
            for (int e = 1; e < NEXP; e++) if (p[e] > p[e0]) e0 = e;  // ties -> lowest idx
            int e1 = (e0 == 0) ? 1 : 0;
#pragma unroll
            for (int e = 0; e < NEXP; e++) if (e != e0 && p[e] > p[e1]) e1 = e;
            const float p0 = p[e0], p1 = p[e1];
            const float wsum = p0 + p1 + 1e-6f;
            const float w0 = p0 / wsum, w1 = p1 / wsum;
            wt0[n] = w0; wt1[n] = w1;
            biasv[n] = w0 * p0 + w1 * p1;
            sel[n] = e0 | (e1 << 8);
        }
    }
}

// ---------------- list build + fused tile planning (last block plans) ------------------
// Plans BOTH maps: tmap256 (global 256-row m-tiles; [0,64) always valid -> fat kernel)
// and tmap128 (the <=8 leftover 256-tiles split into <=16 valid 128-row tiles -> thin).
__global__ __launch_bounds__(256) void build_lists(const int* __restrict__ sel,
                                                   int* __restrict__ lists,
                                                   int* __restrict__ ctrl,
                                                   int* __restrict__ tmap,
                                                   int* __restrict__ tmap128) {
    const int n  = blockIdx.x * 256 + threadIdx.x;
    const int wv = threadIdx.x >> 6;
    const int l  = threadIdx.x & 63;
    const int s  = sel[n];
    const int e0 = s & 0xFF, e1 = s >> 8;
    __shared__ int wcnt[NEXP][4];
    __shared__ int ebase[NEXP];
    int pf0 = 0, pf1 = 0;
    const unsigned long long ltmask = (1ULL << l) - 1ULL;
#pragma unroll
    for (int e = 0; e < NEXP; e++) {
        const int slot = (e0 == e) ? 0 : ((e1 == e) ? 1 : -1);
        const unsigned long long bal = __ballot(slot >= 0);
        const int pf = __popcll(bal & ltmask);
        if (slot == 0) pf0 = pf;
        if (slot == 1) pf1 = pf;
        if (l == 0) wcnt[e][wv] = __popcll(bal);
    }
    __syncthreads();
    if (threadIdx.x < NEXP) {
        const int e = threadIdx.x;
        const int tot = wcnt[e][0] + wcnt[e][1] + wcnt[e][2] + wcnt[e][3];
        ebase[e] = atomicAdd(&ctrl[e * 16], tot);   // counters 64B apart
    }
    __syncthreads();
    int off0 = ebase[e0], off1 = ebase[e1];
#pragma unroll
    for (int i = 0; i < 4; i++) {
        off0 += (i < wv) ? wcnt[e0][i] : 0;
        off1 += (i < wv) ? wcnt[e1][i] : 0;
    }
    lists[e0 * NTOK + off0 + pf0] = n;              // slot 0
    lists[e1 * NTOK + off1 + pf1] = n | 0x10000;    // slot 1

    // ---- last block to finish plans the dense tile maps ----
    __shared__ int lastflag;
    __threadfence();
    if (threadIdx.x == 0) lastflag = (atomicAdd(&ctrl[128], 1) == (int)gridDim.x - 1);
    __syncthreads();
    if (lastflag) {
        __shared__ int tbase[NEXP + 1];
        __shared__ int cnts[NEXP];
        if (threadIdx.x == 0) {
            int acc = 0;
            for (int e = 0; e < NEXP; e++) {
                tbase[e] = acc;
                cnts[e] = atomicAdd(&ctrl[e * 16], 0);  // device-scope read
                acc += (cnts[e] + 255) / 256;
            }
            tbase[NEXP] = acc;   // total 256-tiles; always in [64, 72]
        }
        __syncthreads();
        for (int i = threadIdx.x; i < MAXT256; i += 256) {
            int v = -1;
#pragma unroll
            for (int e = 0; e < NEXP; e++)
                if (i >= tbase[e] && i < tbase[e + 1]) v = (e << 16) | (i - tbase[e]);
            tmap[i] = v;
        }
        if (threadIdx.x < 16) {
            const int j = threadIdx.x;
            const int i256 = FATT + (j >> 1);    // leftover 256-tile index
            int v = -1;
            if (i256 < tbase[NEXP]) {
                int ve = 0;
#pragma unroll
                for (int e = 0; e < NEXP; e++)
                    if (i256 >= tbase[e] && i256 < tbase[e + 1]) ve = e;
                const int m256 = i256 - tbase[ve];
                const int m128 = m256 * 2 + (j & 1);     // in 128-row units
                if (m128 * 128 < cnts[ve]) v = (ve << 16) | m128;
            }
            tmap128[j] = v;
        }
    }
}

// -------- FAT grouped GEMM: 256x256, 8 waves of 128x64, 8-phase schedule (R5) ---------
// Verified structure (R5 passed refcheck). Grid 64x4 = 256 blocks = exactly one
// 1-block-per-CU round (>=64 total 256-tiles guaranteed: sum ceil(cnt/256) >= 64).
// Counted vmcnt(2) at p3/p7 only; swizzle pg = g ^ (row&7) both-sides involution.
__global__ __launch_bounds__(512, 2) void moe_gemm_fat(const u16* __restrict__ x_bf,
                                                       const u16* __restrict__ wt_bf,
                                                       const int* __restrict__ lists,
                                                       const int* __restrict__ ctrl,
                                                       const int* __restrict__ tmap,
                                                       const float* __restrict__ wt0,
                                                       const float* __restrict__ wt1,
                                                       const float* __restrict__ biasv,
                                                       __half* __restrict__ stage0,
                                                       __half* __restrict__ stage1) {
    const int ent = tmap[blockIdx.x];
    if (ent < 0) return;
    const int e = ent >> 16;
    const int tile_m = (ent & 0xFFFF) * 256;
    const int cnt = ctrl[e * 16];
    const int tn = blockIdx.y * 256;

    __shared__ u16 lA[4 * HTILE];   // [parity][half] 64 KB
    __shared__ u16 lB[4 * HTILE];   // 64 KB
    __shared__ int   toks[256];
    __shared__ float wgt[256];
    __shared__ float bia[256];
    __shared__ int   slt[256];

    const int t  = threadIdx.x;     // 0..511
    const int wv = t >> 6;          // 0..7
    const int l  = t & 63;

    if (t < 256) {
        const int idx = tile_m + t;
        int tok = 0; float w = 0.f, b = 0.f; int sl = 0;
        if (idx < cnt) {
            const int entry = lists[e * NTOK + idx];
            tok = entry & 0xFFFF;
            sl = entry >> 16;
            w = sl ? wt1[tok] : wt0[tok];
            b = sl ? 0.f : biasv[tok];
        }
        toks[t] = tok; wgt[t] = w; bia[t] = b; slt[t] = sl;
    }
    __syncthreads();

    // staging lane constants: half-tile = 1024 slots of 16B; slot s -> row = s>>3,
    // phys granule pg = s&7, logical g = pg ^ (row&7). Wave-load i covers slots
    // [(i*8+wv)*64, +64), lane offset implicit l*16B.
    const u16* const wbase = wt_bf + ((size_t)e << 20);
    const u16* pA[2][2]; const u16* pB[2][2];
    int dst0, dst1;
    {
        const int s0 = (0 * 8 + wv) * 64 + l;
        const int s1 = (1 * 8 + wv) * 64 + l;
        const int r0 = s0 >> 3, r1 = s1 >> 3;
        const int g0s = (s0 & 7) ^ (r0 & 7);
        const int g1s = (s1 & 7) ^ (r1 & 7);
        dst0 = (0 * 8 + wv) * 512;
        dst1 = (1 * 8 + wv) * 512;
#pragma unroll
        for (int h = 0; h < 2; h++) {
            pA[0][h] = x_bf + (size_t)toks[h * 128 + r0] * HDIM + g0s * 8;
            pA[1][h] = x_bf + (size_t)toks[h * 128 + r1] * HDIM + g1s * 8;
            pB[0][h] = wbase + (size_t)(tn + h * 128 + r0) * HDIM + g0s * 8;
            pB[1][h] = wbase + (size_t)(tn + h * 128 + r1) * HDIM + g1s * 8;
        }
    }

#define STAGE_A(par, h, ktile) do { \
    gll16(pA[0][h] + (ktile) * 64, lA + (par) * 2 * HTILE + (h) * HTILE + dst0); \
    gll16(pA[1][h] + (ktile) * 64, lA + (par) * 2 * HTILE + (h) * HTILE + dst1); } while (0)
#define STAGE_B(par, h, ktile) do { \
    gll16(pB[0][h] + (ktile) * 64, lB + (par) * 2 * HTILE + (h) * HTILE + dst0); \
    gll16(pB[1][h] + (ktile) * 64, lB + (par) * 2 * HTILE + (h) * HTILE + dst1); } while (0)

    // fragment-read lane constants (swizzled, loop-invariant)
    const int wm2 = wv >> 2;        // 0,1 -> m offset wm2*128 (A half = wm2)
    const int wn4 = wv & 3;         // 0..3 -> n offset wn4*64 (B half = wn4>>1)
    const int fm = l & 15;
    const int fq = l >> 4;          // 0..3
    const int f7 = fm & 7;
    const int pg0 = ((0 + fq) ^ f7) * 8;     // ks=0 granule offset (u16)
    const int pg1 = ((4 + fq) ^ f7) * 8;     // ks=1
    const int arow = fm * 64;
    const int brow = (wn4 & 1) * 4096 + fm * 64;
    const u16* const Abase = lA + wm2 * HTILE;
    const u16* const Bbase = lB + (wn4 >> 1) * HTILE;

    short8 afr[4][2];       // current A m-quadrant (4 frags x 2 k-steps)
    short8 bfr[2][2][2];    // both B n-quadrants (nq, nfL, ks)

#define LDA_H(par, mq) do { \
    _Pragma("unroll") \
    for (int mfL = 0; mfL < 4; mfL++) { \
        afr[mfL][0] = *(const short8*)(Abase + (par) * 2 * HTILE + ((mq) * 4 + mfL) * 1024 + arow + pg0); \
        afr[mfL][1] = *(const short8*)(Abase + (par) * 2 * HTILE + ((mq) * 4 + mfL) * 1024 + arow + pg1); \
    } } while (0)
#define LDB_H(par, nq) do { \
    _Pragma("unroll") \
    for (int nfL = 0; nfL < 2; nfL++) { \
        bfr[nq][nfL][0] = *(const short8*)(Bbase + (par) * 2 * HTILE + ((nq) * 2 + nfL) * 1024 + brow + pg0); \
        bfr[nq][nfL][1] = *(const short8*)(Bbase + (par) * 2 * HTILE + ((nq) * 2 + nfL) * 1024 + brow + pg1); \
    } } while (0)

    float4v acc[8][4];
#pragma unroll
    for (int i = 0; i < 8; i++)
#pragma unroll
        for (int j = 0; j < 4; j++) { float4v z = {0.f, 0.f, 0.f, 0.f}; acc[i][j] = z; }

#define MFMA_Q(mq, nq) do { \
    __builtin_amdgcn_s_setprio(1); \
    _Pragma("unroll") \
    for (int ks = 0; ks < 2; ks++) \
    _Pragma("unroll") \
    for (int mfL = 0; mfL < 4; mfL++) \
    _Pragma("unroll") \
    for (int nfL = 0; nfL < 2; nfL++) \
        acc[(mq) * 4 + mfL][(nq) * 2 + nfL] = __builtin_amdgcn_mfma_f32_16x16x32_bf16( \
            afr[mfL][ks], bfr[nq][nfL][ks], acc[(mq) * 4 + mfL][(nq) * 2 + nfL], 0, 0, 0); \
    __builtin_amdgcn_s_setprio(0); } while (0)

#define BARx() __builtin_amdgcn_s_barrier()
#define LGKM0 do { asm volatile("s_waitcnt lgkmcnt(0)" ::: "memory"); \
                   __builtin_amdgcn_sched_barrier(0); } while (0)
#define VM2 asm volatile("s_waitcnt vmcnt(2)" ::: "memory")
#define VM0 asm volatile("s_waitcnt vmcnt(0)" ::: "memory")

    // prologue: tile 0 (all 4 halves) + tile 1's A-half0 (matches virtual p7)
    STAGE_A(0, 0, 0); STAGE_A(0, 1, 0);
    STAGE_B(0, 0, 0); STAGE_B(0, 1, 0);
    STAGE_A(1, 0, 1);
    VM0; BARx();

#pragma unroll
    for (int it = 0; it < NITF; ++it) {
        const bool st = (it < NITF - 1);
        // p0: consume K-tile 2it (parity 0), quadrant (0,0)
        LDA_H(0, 0); LDB_H(0, 0);
        STAGE_A(1, 1, 2 * it + 1);
        BARx(); LGKM0;
        MFMA_Q(0, 0);
        BARx();
        // p1: quadrant (0,1)
        LDB_H(0, 1);
        STAGE_B(1, 0, 2 * it + 1);
        BARx(); LGKM0;
        MFMA_Q(0, 1);
        BARx();
        // p2: quadrant (1,1)
        LDA_H(0, 1);
        STAGE_B(1, 1, 2 * it + 1);
        BARx(); LGKM0;
        MFMA_Q(1, 1);
        BARx();
        // p3: quadrant (1,0) -- counted vmcnt seals tile 2it+1
        if (st) STAGE_A(0, 0, 2 * it + 2);
        BARx();
        MFMA_Q(1, 0);
        if (st) { VM2; } else { VM0; }
        BARx();
        // p4: consume K-tile 2it+1 (parity 1), quadrant (0,0)
        LDA_H(1, 0); LDB_H(1, 0);
        if (st) STAGE_A(0, 1, 2 * it + 2);
        BARx(); LGKM0;
        MFMA_Q(0, 0);
        BARx();
        // p5: quadrant (0,1)
        LDB_H(1, 1);
        if (st) STAGE_B(0, 0, 2 * it + 2);
        BARx(); LGKM0;
        MFMA_Q(0, 1);
        BARx();
        // p6: quadrant (1,1)
        LDA_H(1, 1);
        if (st) STAGE_B(0, 1, 2 * it + 2);
        BARx(); LGKM0;
        MFMA_Q(1, 1);
        BARx();
        // p7: quadrant (1,0); counted vmcnt seals tile 2it+2
        if (st) STAGE_A(1, 0, 2 * it + 3);
        BARx();
        MFMA_Q(1, 0);
        if (st) { VM2; } else { VM0; }
        BARx();
    }

    // epilogue: stage[slot][tok][h] = fp16(acc*w + b)  -- plain stores, race-free
#pragma unroll
    for (int mf = 0; mf < 8; mf++) {
#pragma unroll
        for (int r = 0; r < 4; r++) {
            const int m_local = wm2 * 128 + mf * 16 + fq * 4 + r;
            if (tile_m + m_local < cnt) {
                const int tok = toks[m_local];
                const float w = wgt[m_local], b = bia[m_local];
                __half* sp = (slt[m_local] ? stage1 : stage0) + (size_t)tok * HDIM;
#pragma unroll
                for (int nf = 0; nf < 4; nf++) {
                    const int h = tn + wn4 * 64 + nf * 16 + fm;
                    sp[h] = __float2half(acc[mf][nf][r] * w + b);
                }
            }
        }
    }
#undef STAGE_A
#undef STAGE_B
#undef LDA_H
#undef LDB_H
#undef MFMA_Q
#undef BARx
#undef LGKM0
#undef VM2
#undef VM0
}

// -------- THIN grouped GEMM: 128x128, 4 waves of 64x64, R3 reg-dbuf engine ------------
// Handles the <=16 leftover 128-row tiles via tmap128 (most launched blocks early-exit).
__global__ __launch_bounds__(256, 3) void moe_gemm_thin(const u16* __restrict__ x_bf,
                                                        const u16* __restrict__ wt_bf,
                                                        const int* __restrict__ lists,
                                                        const int* __restrict__ ctrl,
                                                        const int* __restrict__ tmap128,
                                                        const float* __restrict__ wt0,
                                                        const float* __restrict__ wt1,
                                                        const float* __restrict__ biasv,
                                                        __half* __restrict__ stage0,
                                                        __half* __restrict__ stage1) {
    const int ent = tmap128[blockIdx.x];
    if (ent < 0) return;
    const int e = ent >> 16;
    const int tile_m = (ent & 0xFFFF) * TMT;
    const int cnt = ctrl[e * 16];
    const int tn = blockIdx.y * TMT;

    __shared__ u16 lA[3 * LAT];   // 24 KB
    __shared__ u16 lB[3 * LAT];   // 24 KB
    __shared__ int   toks[TMT];
    __shared__ float wgt[TMT];
    __shared__ float bia[TMT];
    __shared__ int   slt[TMT];

    const int t  = threadIdx.x;
    const int wv = t >> 6;
    const int l  = t & 63;

    if (t < TMT) {
        const int idx = tile_m + t;
        int tok = 0; float w = 0.f, b = 0.f; int sl = 0;
        if (idx < cnt) {
            const int entry = lists[e * NTOK + idx];
            tok = entry & 0xFFFF;
            sl = entry >> 16;
            w = sl ? wt1[tok] : wt0[tok];
            b = sl ? 0.f : biasv[tok];
        }
        toks[t] = tok; wgt[t] = w; bia[t] = b; slt[t] = sl;
    }
    __syncthreads();

    const u16* gA[2]; const u16* gB[2]; int dAB[2];
#pragma unroll
    for (int i = 0; i < 2; i++) {
        const int slot = (i * 4 + wv) * 64 + l;
        const int row  = slot >> 2;
        const int c    = (slot & 3) ^ ((row >> 1) & 3);
        gA[i] = x_bf + (size_t)toks[row] * HDIM + c * 8;
        gB[i] = wt_bf + ((size_t)e << 20) + (size_t)(tn + row) * HDIM + c * 8;
        dAB[i] = (i * 4 + wv) * 512;
    }

    const int wm = (wv & 1) * 64;
    const int wn = (wv >> 1) * 64;
    const int fm = l & 15;
    const int fq = l >> 4;
    int aoff[4], boff[4];
#pragma unroll
    for (int i = 0; i < 4; i++) {
        const int ra = wm + i * 16 + fm;
        const int rb = wn + i * 16 + fm;
        aoff[i] = ra * BKT + ((fq ^ ((ra >> 1) & 3)) * 8);
        boff[i] = rb * BKT + ((fq ^ ((rb >> 1) & 3)) * 8);
    }

    float4v acc[4][4];
#pragma unroll
    for (int i = 0; i < 4; i++)
#pragma unroll
        for (int j = 0; j < 4; j++) { float4v z = {0.f, 0.f, 0.f, 0.f}; acc[i][j] = z; }

    short8 afr[2][4], bfr[2][4];

#pragma unroll
    for (int tk = 0; tk < 3; tk++) {
#pragma unroll
        for (int i = 0; i < 2; i++) {
            gll16(gA[i] + tk * BKT, lA + tk * LAT + dAB[i]);
            gll16(gB[i] + tk * BKT, lB + tk * LAT + dAB[i]);
        }
    }
    asm volatile("s_waitcnt vmcnt(8)\n\ts_barrier" ::: "memory");
#pragma unroll
    for (int i = 0; i < 4; i++) {
        afr[0][i] = *(const short8*)&lA[aoff[i]];
        bfr[0][i] = *(const short8*)&lB[boff[i]];
    }

#pragma unroll
    for (int it = 0; it < NITT; ++it) {
        const int cs = it & 1;
        const int ns = cs ^ 1;

        if (it == 0) {
            asm volatile("s_waitcnt vmcnt(4)\n\ts_barrier" ::: "memory");
        } else if (it < NITT - 1) {
            asm volatile("s_waitcnt vmcnt(0)\n\ts_barrier" ::: "memory");
        }

        if (it >= 1 && it + 2 < NITT) {
            const int nb = (it + 2) % 3;
            const int nk = (it + 2) * BKT;
#pragma unroll
            for (int i = 0; i < 2; i++) {
                gll16(gA[i] + nk, lA + nb * LAT + dAB[i]);
                gll16(gB[i] + nk, lB + nb * LAT + dAB[i]);
            }
        }

        if (it + 1 < NITT) {
            const u16* ca = lA + ((it + 1) % 3) * LAT;
            const u16* cb = lB + ((it + 1) % 3) * LAT;
#pragma unroll
            for (int i = 0; i < 4; i++) {
                afr[ns][i] = *(const short8*)&ca[aoff[i]];
                bfr[ns][i] = *(const short8*)&cb[boff[i]];
            }
            asm volatile("s_waitcnt lgkmcnt(8)" ::: "memory");
        } else {
            asm volatile("s_waitcnt lgkmcnt(0)" ::: "memory");
        }
        __builtin_amdgcn_sched_barrier(0);

        __builtin_amdgcn_s_setprio(1);
#pragma unroll
        for (int i = 0; i < 4; i++)
#pragma unroll
            for (int nf = 0; nf < 4; nf++)
                acc[i][nf] = __builtin_amdgcn_mfma_f32_16x16x32_bf16(
                    afr[cs][i], bfr[cs][nf], acc[i][nf], 0, 0, 0);
        __builtin_amdgcn_s_setprio(0);
    }

#pragma unroll
    for (int mf = 0; mf < 4; mf++) {
#pragma unroll
        for (int r = 0; r < 4; r++) {
            const int m_local = wm + mf * 16 + fq * 4 + r;
            if (tile_m + m_local < cnt) {
                const int tok = toks[m_local];
                const float w = wgt[m_local], b = bia[m_local];
                __half* sp = (slt[m_local] ? stage1 : stage0) + (size_t)tok * HDIM;
#pragma unroll
                for (int nf = 0; nf < 4; nf++) {
                    const int h = tn + wn + nf * 16 + fm;
                    sp[h] = __float2half(acc[mf][nf][r] * w + b);
                }
            }
        }
    }
}

// ---------------- combine: out = stage0 + stage1 (fully coalesced) ----------------
__global__ __launch_bounds__(256) void combine(const __half* __restrict__ s0,
                                               const __half* __restrict__ s1,
                                               float* __restrict__ out) {
    const size_t idx = ((size_t)blockIdx.x * 256 + threadIdx.x) * 8;
    union { uint4 v; __half h[8]; } a, b;
    a.v = *(const uint4*)(s0 + idx);
    b.v = *(const uint4*)(s1 + idx);
    float4 o0, o1;
    o0.x = __half2float(a.h[0]) + __half2float(b.h[0]);
    o0.y = __half2float(a.h[1]) + __half2float(b.h[1]);
    o0.z = __half2float(a.h[2]) + __half2float(b.h[2]);
    o0.w = __half2float(a.h[3]) + __half2float(b.h[3]);
    o1.x = __half2float(a.h[4]) + __half2float(b.h[4]);
    o1.y = __half2float(a.h[5]) + __half2float(b.h[5]);
    o1.z = __half2float(a.h[6]) + __half2float(b.h[6]);
    o1.w = __half2float(a.h[7]) + __half2float(b.h[7]);
    *(float4*)(out + idx)     = o0;
    *(float4*)(out + idx + 4) = o1;
}

extern "C" void kernel_launch(void* const* d_in, const int* in_sizes, int n_in,
                              void* d_out, int out_size, void* d_ws, size_t ws_size,
                              hipStream_t stream) {
    const float* x  = (const float*)d_in[0];   // [4,2048,1024]
    const float* rw = (const float*)d_in[1];   // [8,1024]
    const float* ew = (const float*)d_in[2];   // [8,1024,1024]
    float* out = (float*)d_out;

    char* ws = (char*)d_ws;
    u16*    x_bf    = (u16*)ws;                          // 16 MiB
    u16*    w_bf    = (u16*)(ws + 16777216);             // 16 MiB
    __half* stage0  = (__half*)(ws + 33554432);          // 16 MiB
    __half* stage1  = (__half*)(ws + 50331648);          // 16 MiB
    float*  wt0     = (float*)(ws + 67108864);           // 32 KiB
    float*  wt1     = (float*)(ws + 67141632);           // 32 KiB
    float*  biasv   = (float*)(ws + 67174400);           // 32 KiB
    int*    sel     = (int*)(ws + 67207168);             // 32 KiB
    int*    lists   = (int*)(ws + 67239936);             // 256 KiB
    int*    ctrl    = (int*)(ws + 67502080);             // 528 B (pad to 640)
    int*    tmap    = (int*)(ws + 67502720);             // 288 B (72 x 256-tiles)
    int*    tmap128 = (int*)(ws + 67503104);             // 64 B (16 x 128-tiles)

    prep<<<WBLK + RBLK, 256, 0, stream>>>(x, rw, ew, x_bf, w_bf, wt0, wt1, biasv, sel, ctrl);
    build_lists<<<NTOK / 256, 256, 0, stream>>>(sel, lists, ctrl, tmap, tmap128);
    moe_gemm_fat<<<dim3(FATT, 4, 1), 512, 0, stream>>>(
        x_bf, w_bf, lists, ctrl, tmap, wt0, wt1, biasv, stage0, stage1);
    moe_gemm_thin<<<dim3(16, 8, 1), 256, 0, stream>>>(
        x_bf, w_bf, lists, ctrl, tmap128, wt0, wt1, biasv, stage0, stage1);
    combine<<<(NTOK * HDIM) / (256 * 8), 256, 0, stream>>>(stage0, stage1, out);
}

// Round 11
// 189.624 us; speedup vs baseline: 1.0454x; 1.0454x over previous
//
#include <hip/hip_runtime.h>
#include <hip/hip_fp16.h>
#include <cstdint>

typedef unsigned short u16;
typedef __attribute__((ext_vector_type(8))) short short8;
typedef __attribute__((ext_vector_type(4))) float float4v;

#define NTOK 8192
#define HDIM 1024
#define NEXP 8
// fat kernel (8-phase, 256x256, BK=64)
#define HTILE (128 * 64)         // one half-tile: 8192 u16 = 16 KB
#define NITF 8                   // 8 main iters x 2 K-tiles
#define MAXT256 72               // max 256-m-tiles: 64 + 8 rounding partials
#define FATT 64                  // fat kernel covers global 256-tiles [0,64) -- always valid
// thin kernel (R3 engine, 128x128, BK=32, K-split x4)
#define TMT 128
#define BKT 32
#define KST 4                    // thin K-split
#define NITT (HDIM / BKT / KST)  // 8 k-tiles per thin block
#define LAT (TMT * BKT)          // 4096 u16 = 8 KB
#define LROWS 2048               // max leftover rows (16 x 128)
// prep
#define WBLK 2048  // W-transpose blocks (64x64 tiles x 8 experts)
#define RBLK 2048  // router blocks (4 tokens each)

__device__ __forceinline__ u16 f2bf(float f) {
    union { float f; uint32_t u; } v; v.f = f;
    uint32_t u = v.u;
    return (u16)((u + 0x7FFFu + ((u >> 16) & 1u)) >> 16);
}

// async global->LDS, 16B per lane; LDS dest = wave-uniform base + lane*16
__device__ __forceinline__ void gll16(const u16* g, u16* l) {
    __builtin_amdgcn_global_load_lds(
        (const __attribute__((address_space(1))) uint32_t*)g,
        (__attribute__((address_space(3))) uint32_t*)l,
        16, 0, 0);
}

// ---------------- fused prep: W transpose+quantize AND router AND ctrl zeroing ---------
__global__ __launch_bounds__(256) void prep(const float* __restrict__ x,
                                            const float* __restrict__ rw,
                                            const float* __restrict__ ew,
                                            u16* __restrict__ x_bf,
                                            u16* __restrict__ w_bf,
                                            float* __restrict__ wt0,
                                            float* __restrict__ wt1,
                                            float* __restrict__ biasv,
                                            int* __restrict__ sel,
                                            int* __restrict__ ctrl) {
    if (blockIdx.x == 0 && threadIdx.x < 132) ctrl[threadIdx.x] = 0;  // counts[8x16] + done

    if (blockIdx.x < WBLK) {
        __shared__ float tile[64][65];       // +1 pad, 2-way aliasing = free
        const int bid = blockIdx.x;
        const int e  = bid >> 8;                   // 8 experts x 256 tiles
        const int k0 = ((bid >> 4) & 15) * 64;
        const int n0 = (bid & 15) * 64;
        const int kr = threadIdx.x >> 2;           // 0..63
        const int ng = (threadIdx.x & 3) * 16;     // 0,16,32,48
        const float* src = ew + ((size_t)e << 20) + (size_t)(k0 + kr) * HDIM + n0 + ng;
#pragma unroll
        for (int j = 0; j < 4; j++) {
            const float4 v = *(const float4*)(src + 4 * j);
            tile[kr][ng + 4*j]     = v.x;
            tile[kr][ng + 4*j + 1] = v.y;
            tile[kr][ng + 4*j + 2] = v.z;
            tile[kr][ng + 4*j + 3] = v.w;
        }
        __syncthreads();
        const int nr = threadIdx.x >> 2;           // 0..63
        const int kg = (threadIdx.x & 3) * 16;
        u16* dst = w_bf + ((size_t)e << 20) + (size_t)(n0 + nr) * HDIM + k0 + kg;
#pragma unroll
        for (int j = 0; j < 4; j++) {
            ushort4 o;
            o.x = f2bf(tile[kg + 4*j][nr]);
            o.y = f2bf(tile[kg + 4*j + 1][nr]);
            o.z = f2bf(tile[kg + 4*j + 2][nr]);
            o.w = f2bf(tile[kg + 4*j + 3][nr]);
            *(ushort4*)(dst + 4 * j) = o;
        }
    } else {
        const int wv = threadIdx.x >> 6;
        const int l  = threadIdx.x & 63;
        const int n  = (blockIdx.x - WBLK) * 4 + wv;  // one wave per token
        const float4* xr = (const float4*)(x + (size_t)n * HDIM);
        ushort4* xo = (ushort4*)(x_bf + (size_t)n * HDIM);

        float4 xv[4];
#pragma unroll
        for (int t = 0; t < 4; t++) {
            xv[t] = xr[t * 64 + l];
            ushort4 p;
            p.x = f2bf(xv[t].x); p.y = f2bf(xv[t].y);
            p.z = f2bf(xv[t].z); p.w = f2bf(xv[t].w);
            xo[t * 64 + l] = p;
        }

        float logits[NEXP];
#pragma unroll
        for (int e = 0; e < NEXP; e++) {
            const float4* rwe = (const float4*)(rw + e * HDIM);
            float acc = 0.f;
#pragma unroll
            for (int t = 0; t < 4; t++) {
                const float4 r = rwe[t * 64 + l];
                acc += xv[t].x * r.x + xv[t].y * r.y + xv[t].z * r.z + xv[t].w * r.w;
            }
#pragma unroll
            for (int s = 32; s > 0; s >>= 1) acc += __shfl_xor(acc, s, 64);
            logits[e] = acc;
        }

        if (l == 0) {
            float mx = logits[0];
#pragma unroll
            for (int e = 1; e < NEXP; e++) mx = fmaxf(mx, logits[e]);
            float p[NEXP]; float sum = 0.f;
#pragma unroll
            for (int e = 0; e < NEXP; e++) { p[e] = expf(logits[e] - mx); sum += p[e]; }
            const float inv = 1.f / sum;
#pragma unroll
            for (int e = 0; e < NEXP; e++) p[e] *= inv;
            int e0 = 0;
#pragma unroll
            for (int e = 1; e < NEXP; e++) if (p[e] > p[e0]) e0 = e;  // ties -> lowest idx
            int e1 = (e0 == 0) ? 1 : 0;
#pragma unroll
            for (int e = 0; e < NEXP; e++) if (e != e0 && p[e] > p[e1]) e1 = e;
            const float p0 = p[e0], p1 = p[e1];
            const float wsum = p0 + p1 + 1e-6f;
            const float w0 = p0 / wsum, w1 = p1 / wsum;
            wt0[n] = w0; wt1[n] = w1;
            biasv[n] = w0 * p0 + w1 * p1;
            sel[n] = e0 | (e1 << 8);
        }
    }
}

// ---------------- list build + fused tile planning (last block plans) ------------------
__global__ __launch_bounds__(256) void build_lists(const int* __restrict__ sel,
                                                   int* __restrict__ lists,
                                                   int* __restrict__ ctrl,
                                                   int* __restrict__ tmap,
                                                   int* __restrict__ tmap128) {
    const int n  = blockIdx.x * 256 + threadIdx.x;
    const int wv = threadIdx.x >> 6;
    const int l  = threadIdx.x & 63;
    const int s  = sel[n];
    const int e0 = s & 0xFF, e1 = s >> 8;
    __shared__ int wcnt[NEXP][4];
    __shared__ int ebase[NEXP];
    int pf0 = 0, pf1 = 0;
    const unsigned long long ltmask = (1ULL << l) - 1ULL;
#pragma unroll
    for (int e = 0; e < NEXP; e++) {
        const int slot = (e0 == e) ? 0 : ((e1 == e) ? 1 : -1);
        const unsigned long long bal = __ballot(slot >= 0);
        const int pf = __popcll(bal & ltmask);
        if (slot == 0) pf0 = pf;
        if (slot == 1) pf1 = pf;
        if (l == 0) wcnt[e][wv] = __popcll(bal);
    }
    __syncthreads();
    if (threadIdx.x < NEXP) {
        const int e = threadIdx.x;
        const int tot = wcnt[e][0] + wcnt[e][1] + wcnt[e][2] + wcnt[e][3];
        ebase[e] = atomicAdd(&ctrl[e * 16], tot);   // counters 64B apart
    }
    __syncthreads();
    int off0 = ebase[e0], off1 = ebase[e1];
#pragma unroll
    for (int i = 0; i < 4; i++) {
        off0 += (i < wv) ? wcnt[e0][i] : 0;
        off1 += (i < wv) ? wcnt[e1][i] : 0;
    }
    lists[e0 * NTOK + off0 + pf0] = n;              // slot 0
    lists[e1 * NTOK + off1 + pf1] = n | 0x10000;    // slot 1

    // ---- last block to finish plans the dense tile maps ----
    __shared__ int lastflag;
    __threadfence();
    if (threadIdx.x == 0) lastflag = (atomicAdd(&ctrl[128], 1) == (int)gridDim.x - 1);
    __syncthreads();
    if (lastflag) {
        __shared__ int tbase[NEXP + 1];
        __shared__ int cnts[NEXP];
        if (threadIdx.x == 0) {
            int acc = 0;
            for (int e = 0; e < NEXP; e++) {
                tbase[e] = acc;
                cnts[e] = atomicAdd(&ctrl[e * 16], 0);  // device-scope read
                acc += (cnts[e] + 255) / 256;
            }
            tbase[NEXP] = acc;   // total 256-tiles; always in [64, 72]
        }
        __syncthreads();
        for (int i = threadIdx.x; i < MAXT256; i += 256) {
            int v = -1;
#pragma unroll
            for (int e = 0; e < NEXP; e++)
                if (i >= tbase[e] && i < tbase[e + 1]) v = (e << 16) | (i - tbase[e]);
            tmap[i] = v;
        }
        if (threadIdx.x < 16) {
            const int j = threadIdx.x;
            const int i256 = FATT + (j >> 1);    // leftover 256-tile index
            int v = -1;
            if (i256 < tbase[NEXP]) {
                int ve = 0;
#pragma unroll
                for (int e = 0; e < NEXP; e++)
                    if (i256 >= tbase[e] && i256 < tbase[e + 1]) ve = e;
                const int m256 = i256 - tbase[ve];
                const int m128 = m256 * 2 + (j & 1);     // in 128-row units
                if (m128 * 128 < cnts[ve]) v = (ve << 16) | m128;
            }
            tmap128[j] = v;
        }
    }
}

// -------- FAT grouped GEMM: 256x256, 8 waves of 128x64, 8-phase schedule --------------
// R10 engine verbatim + XCD-aware block remap: flat id b -> XCD k = b%8 owns tiles
// [8k, 8k+8) x all 4 n-quadrants, so each XCD's B working set (~2-4 MB) L2-fits and A
// panels are reused across quadrants within one XCD. Bijective 256<->256.
__global__ __launch_bounds__(512, 2) void moe_gemm_fat(const u16* __restrict__ x_bf,
                                                       const u16* __restrict__ wt_bf,
                                                       const int* __restrict__ lists,
                                                       const int* __restrict__ ctrl,
                                                       const int* __restrict__ tmap,
                                                       const float* __restrict__ wt0,
                                                       const float* __restrict__ wt1,
                                                       const float* __restrict__ biasv,
                                                       __half* __restrict__ stage0,
                                                       __half* __restrict__ stage1) {
    // XCD remap: bid = x + 64*y in dispatch order; XCD ~ bid%8 (heuristic, perf-only)
    const int bid = blockIdx.x + FATT * blockIdx.y;   // 0..255
    const int li  = bid >> 3;                         // 0..31
    const int tile_idx = (bid & 7) * 8 + (li & 7);    // 0..63
    const int quad     = li >> 3;                     // 0..3
    const int ent = tmap[tile_idx];
    if (ent < 0) return;
    const int e = ent >> 16;
    const int tile_m = (ent & 0xFFFF) * 256;
    const int cnt = ctrl[e * 16];
    const int tn = quad * 256;

    __shared__ u16 lA[4 * HTILE];   // [parity][half] 64 KB
    __shared__ u16 lB[4 * HTILE];   // 64 KB
    __shared__ int   toks[256];
    __shared__ float wgt[256];
    __shared__ float bia[256];
    __shared__ int   slt[256];

    const int t  = threadIdx.x;     // 0..511
    const int wv = t >> 6;          // 0..7
    const int l  = t & 63;

    if (t < 256) {
        const int idx = tile_m + t;
        int tok = 0; float w = 0.f, b = 0.f; int sl = 0;
        if (idx < cnt) {
            const int entry = lists[e * NTOK + idx];
            tok = entry & 0xFFFF;
            sl = entry >> 16;
            w = sl ? wt1[tok] : wt0[tok];
            b = sl ? 0.f : biasv[tok];
        }
        toks[t] = tok; wgt[t] = w; bia[t] = b; slt[t] = sl;
    }
    __syncthreads();

    // staging lane constants: half-tile = 1024 slots of 16B; slot s -> row = s>>3,
    // phys granule pg = s&7, logical g = pg ^ (row&7).
    const u16* const wbase = wt_bf + ((size_t)e << 20);
    const u16* pA[2][2]; const u16* pB[2][2];
    int dst0, dst1;
    {
        const int s0 = (0 * 8 + wv) * 64 + l;
        const int s1 = (1 * 8 + wv) * 64 + l;
        const int r0 = s0 >> 3, r1 = s1 >> 3;
        const int g0s = (s0 & 7) ^ (r0 & 7);
        const int g1s = (s1 & 7) ^ (r1 & 7);
        dst0 = (0 * 8 + wv) * 512;
        dst1 = (1 * 8 + wv) * 512;
#pragma unroll
        for (int h = 0; h < 2; h++) {
            pA[0][h] = x_bf + (size_t)toks[h * 128 + r0] * HDIM + g0s * 8;
            pA[1][h] = x_bf + (size_t)toks[h * 128 + r1] * HDIM + g1s * 8;
            pB[0][h] = wbase + (size_t)(tn + h * 128 + r0) * HDIM + g0s * 8;
            pB[1][h] = wbase + (size_t)(tn + h * 128 + r1) * HDIM + g1s * 8;
        }
    }

#define STAGE_A(par, h, ktile) do { \
    gll16(pA[0][h] + (ktile) * 64, lA + (par) * 2 * HTILE + (h) * HTILE + dst0); \
    gll16(pA[1][h] + (ktile) * 64, lA + (par) * 2 * HTILE + (h) * HTILE + dst1); } while (0)
#define STAGE_B(par, h, ktile) do { \
    gll16(pB[0][h] + (ktile) * 64, lB + (par) * 2 * HTILE + (h) * HTILE + dst0); \
    gll16(pB[1][h] + (ktile) * 64, lB + (par) * 2 * HTILE + (h) * HTILE + dst1); } while (0)

    // fragment-read lane constants (swizzled, loop-invariant)
    const int wm2 = wv >> 2;        // 0,1 -> m offset wm2*128 (A half = wm2)
    const int wn4 = wv & 3;         // 0..3 -> n offset wn4*64 (B half = wn4>>1)
    const int fm = l & 15;
    const int fq = l >> 4;          // 0..3
    const int f7 = fm & 7;
    const int pg0 = ((0 + fq) ^ f7) * 8;     // ks=0 granule offset (u16)
    const int pg1 = ((4 + fq) ^ f7) * 8;     // ks=1
    const int arow = fm * 64;
    const int brow = (wn4 & 1) * 4096 + fm * 64;
    const u16* const Abase = lA + wm2 * HTILE;
    const u16* const Bbase = lB + (wn4 >> 1) * HTILE;

    short8 afr[4][2];       // current A m-quadrant (4 frags x 2 k-steps)
    short8 bfr[2][2][2];    // both B n-quadrants (nq, nfL, ks)

#define LDA_H(par, mq) do { \
    _Pragma("unroll") \
    for (int mfL = 0; mfL < 4; mfL++) { \
        afr[mfL][0] = *(const short8*)(Abase + (par) * 2 * HTILE + ((mq) * 4 + mfL) * 1024 + arow + pg0); \
        afr[mfL][1] = *(const short8*)(Abase + (par) * 2 * HTILE + ((mq) * 4 + mfL) * 1024 + arow + pg1); \
    } } while (0)
#define LDB_H(par, nq) do { \
    _Pragma("unroll") \
    for (int nfL = 0; nfL < 2; nfL++) { \
        bfr[nq][nfL][0] = *(const short8*)(Bbase + (par) * 2 * HTILE + ((nq) * 2 + nfL) * 1024 + brow + pg0); \
        bfr[nq][nfL][1] = *(const short8*)(Bbase + (par) * 2 * HTILE + ((nq) * 2 + nfL) * 1024 + brow + pg1); \
    } } while (0)

    float4v acc[8][4];
#pragma unroll
    for (int i = 0; i < 8; i++)
#pragma unroll
        for (int j = 0; j < 4; j++) { float4v z = {0.f, 0.f, 0.f, 0.f}; acc[i][j] = z; }

#define MFMA_Q(mq, nq) do { \
    __builtin_amdgcn_s_setprio(1); \
    _Pragma("unroll") \
    for (int ks = 0; ks < 2; ks++) \
    _Pragma("unroll") \
    for (int mfL = 0; mfL < 4; mfL++) \
    _Pragma("unroll") \
    for (int nfL = 0; nfL < 2; nfL++) \
        acc[(mq) * 4 + mfL][(nq) * 2 + nfL] = __builtin_amdgcn_mfma_f32_16x16x32_bf16( \
            afr[mfL][ks], bfr[nq][nfL][ks], acc[(mq) * 4 + mfL][(nq) * 2 + nfL], 0, 0, 0); \
    __builtin_amdgcn_s_setprio(0); } while (0)

#define BARx() __builtin_amdgcn_s_barrier()
#define LGKM0 do { asm volatile("s_waitcnt lgkmcnt(0)" ::: "memory"); \
                   __builtin_amdgcn_sched_barrier(0); } while (0)
#define VM2 asm volatile("s_waitcnt vmcnt(2)" ::: "memory")
#define VM0 asm volatile("s_waitcnt vmcnt(0)" ::: "memory")

    // prologue: tile 0 (all 4 halves) + tile 1's A-half0 (matches virtual p7)
    STAGE_A(0, 0, 0); STAGE_A(0, 1, 0);
    STAGE_B(0, 0, 0); STAGE_B(0, 1, 0);
    STAGE_A(1, 0, 1);
    VM0; BARx();

#pragma unroll
    for (int it = 0; it < NITF; ++it) {
        const bool st = (it < NITF - 1);
        // p0: consume K-tile 2it (parity 0), quadrant (0,0)
        LDA_H(0, 0); LDB_H(0, 0);
        STAGE_A(1, 1, 2 * it + 1);
        BARx(); LGKM0;
        MFMA_Q(0, 0);
        BARx();
        // p1: quadrant (0,1)
        LDB_H(0, 1);
        STAGE_B(1, 0, 2 * it + 1);
        BARx(); LGKM0;
        MFMA_Q(0, 1);
        BARx();
        // p2: quadrant (1,1)
        LDA_H(0, 1);
        STAGE_B(1, 1, 2 * it + 1);
        BARx(); LGKM0;
        MFMA_Q(1, 1);
        BARx();
        // p3: quadrant (1,0) -- counted vmcnt seals tile 2it+1
        if (st) STAGE_A(0, 0, 2 * it + 2);
        BARx();
        MFMA_Q(1, 0);
        if (st) { VM2; } else { VM0; }
        BARx();
        // p4: consume K-tile 2it+1 (parity 1), quadrant (0,0)
        LDA_H(1, 0); LDB_H(1, 0);
        if (st) STAGE_A(0, 1, 2 * it + 2);
        BARx(); LGKM0;
        MFMA_Q(0, 0);
        BARx();
        // p5: quadrant (0,1)
        LDB_H(1, 1);
        if (st) STAGE_B(0, 0, 2 * it + 2);
        BARx(); LGKM0;
        MFMA_Q(0, 1);
        BARx();
        // p6: quadrant (1,1)
        LDA_H(1, 1);
        if (st) STAGE_B(0, 1, 2 * it + 2);
        BARx(); LGKM0;
        MFMA_Q(1, 1);
        BARx();
        // p7: quadrant (1,0); counted vmcnt seals tile 2it+2
        if (st) STAGE_A(1, 0, 2 * it + 3);
        BARx();
        MFMA_Q(1, 0);
        if (st) { VM2; } else { VM0; }
        BARx();
    }

    // epilogue: stage[slot][tok][h] = fp16(acc*w + b)  -- plain stores, race-free
#pragma unroll
    for (int mf = 0; mf < 8; mf++) {
#pragma unroll
        for (int r = 0; r < 4; r++) {
            const int m_local = wm2 * 128 + mf * 16 + fq * 4 + r;
            if (tile_m + m_local < cnt) {
                const int tok = toks[m_local];
                const float w = wgt[m_local], b = bia[m_local];
                __half* sp = (slt[m_local] ? stage1 : stage0) + (size_t)tok * HDIM;
#pragma unroll
                for (int nf = 0; nf < 4; nf++) {
                    const int h = tn + wn4 * 64 + nf * 16 + fm;
                    sp[h] = __float2half(acc[mf][nf][r] * w + b);
                }
            }
        }
    }
#undef STAGE_A
#undef STAGE_B
#undef LDA_H
#undef LDB_H
#undef MFMA_Q
#undef BARx
#undef LGKM0
#undef VM2
#undef VM0
}

// -------- THIN grouped GEMM: 128x128, R3 reg-dbuf engine, K-split x4 ------------------
// Leftover <=16 128-row tiles. kz=0 writes stage (rows disjoint from fat); kz=1..3
// write fp16 partials (w*acc, no bias) into the compact part buffer [3][2048][1024].
// Per-block K=256 -> NITT=8 -> ~11 us tail instead of a full-K ~24-35 us block.
__global__ __launch_bounds__(256, 3) void moe_gemm_thin(const u16* __restrict__ x_bf,
                                                        const u16* __restrict__ wt_bf,
                                                        const int* __restrict__ lists,
                                                        const int* __restrict__ ctrl,
                                                        const int* __restrict__ tmap128,
                                                        const float* __restrict__ wt0,
                                                        const float* __restrict__ wt1,
                                                        const float* __restrict__ biasv,
                                                        __half* __restrict__ stage0,
                                                        __half* __restrict__ stage1,
                                                        __half* __restrict__ part) {
    const int ent = tmap128[blockIdx.x];
    if (ent < 0) return;
    const int e = ent >> 16;
    const int tile_m = (ent & 0xFFFF) * TMT;
    const int cnt = ctrl[e * 16];
    const int tn = blockIdx.y * TMT;
    const int kz = blockIdx.z;                    // 0..3
    const int koff = kz * (HDIM / KST);           // u16 element offset into K

    __shared__ u16 lA[3 * LAT];   // 24 KB
    __shared__ u16 lB[3 * LAT];   // 24 KB
    __shared__ int   toks[TMT];
    __shared__ float wgt[TMT];
    __shared__ float bia[TMT];
    __shared__ int   slt[TMT];

    const int t  = threadIdx.x;
    const int wv = t >> 6;
    const int l  = t & 63;

    if (t < TMT) {
        const int idx = tile_m + t;
        int tok = 0; float w = 0.f, b = 0.f; int sl = 0;
        if (idx < cnt) {
            const int entry = lists[e * NTOK + idx];
            tok = entry & 0xFFFF;
            sl = entry >> 16;
            w = sl ? wt1[tok] : wt0[tok];
            b = (sl || kz) ? 0.f : biasv[tok];    // bias once: slot0, kz0
        }
        toks[t] = tok; wgt[t] = w; bia[t] = b; slt[t] = sl;
    }
    __syncthreads();

    const u16* gA[2]; const u16* gB[2]; int dAB[2];
#pragma unroll
    for (int i = 0; i < 2; i++) {
        const int slot = (i * 4 + wv) * 64 + l;
        const int row  = slot >> 2;
        const int c    = (slot & 3) ^ ((row >> 1) & 3);
        gA[i] = x_bf + (size_t)toks[row] * HDIM + koff + c * 8;
        gB[i] = wt_bf + ((size_t)e << 20) + (size_t)(tn + row) * HDIM + koff + c * 8;
        dAB[i] = (i * 4 + wv) * 512;
    }

    const int wm = (wv & 1) * 64;
    const int wn = (wv >> 1) * 64;
    const int fm = l & 15;
    const int fq = l >> 4;
    int aoff[4], boff[4];
#pragma unroll
    for (int i = 0; i < 4; i++) {
        const int ra = wm + i * 16 + fm;
        const int rb = wn + i * 16 + fm;
        aoff[i] = ra * BKT + ((fq ^ ((ra >> 1) & 3)) * 8);
        boff[i] = rb * BKT + ((fq ^ ((rb >> 1) & 3)) * 8);
    }

    float4v acc[4][4];
#pragma unroll
    for (int i = 0; i < 4; i++)
#pragma unroll
        for (int j = 0; j < 4; j++) { float4v z = {0.f, 0.f, 0.f, 0.f}; acc[i][j] = z; }

    short8 afr[2][4], bfr[2][4];

#pragma unroll
    for (int tk = 0; tk < 3; tk++) {
#pragma unroll
        for (int i = 0; i < 2; i++) {
            gll16(gA[i] + tk * BKT, lA + tk * LAT + dAB[i]);
            gll16(gB[i] + tk * BKT, lB + tk * LAT + dAB[i]);
        }
    }
    asm volatile("s_waitcnt vmcnt(8)\n\ts_barrier" ::: "memory");
#pragma unroll
    for (int i = 0; i < 4; i++) {
        afr[0][i] = *(const short8*)&lA[aoff[i]];
        bfr[0][i] = *(const short8*)&lB[boff[i]];
    }

#pragma unroll
    for (int it = 0; it < NITT; ++it) {
        const int cs = it & 1;
        const int ns = cs ^ 1;

        if (it == 0) {
            asm volatile("s_waitcnt vmcnt(4)\n\ts_barrier" ::: "memory");
        } else if (it < NITT - 1) {
            asm volatile("s_waitcnt vmcnt(0)\n\ts_barrier" ::: "memory");
        }

        if (it >= 1 && it + 2 < NITT) {
            const int nb = (it + 2) % 3;
            const int nk = (it + 2) * BKT;
#pragma unroll
            for (int i = 0; i < 2; i++) {
                gll16(gA[i] + nk, lA + nb * LAT + dAB[i]);
                gll16(gB[i] + nk, lB + nb * LAT + dAB[i]);
            }
        }

        if (it + 1 < NITT) {
            const u16* ca = lA + ((it + 1) % 3) * LAT;
            const u16* cb = lB + ((it + 1) % 3) * LAT;
#pragma unroll
            for (int i = 0; i < 4; i++) {
                afr[ns][i] = *(const short8*)&ca[aoff[i]];
                bfr[ns][i] = *(const short8*)&cb[boff[i]];
            }
            asm volatile("s_waitcnt lgkmcnt(8)" ::: "memory");
        } else {
            asm volatile("s_waitcnt lgkmcnt(0)" ::: "memory");
        }
        __builtin_amdgcn_sched_barrier(0);

        __builtin_amdgcn_s_setprio(1);
#pragma unroll
        for (int i = 0; i < 4; i++)
#pragma unroll
            for (int nf = 0; nf < 4; nf++)
                acc[i][nf] = __builtin_amdgcn_mfma_f32_16x16x32_bf16(
                    afr[cs][i], bfr[cs][nf], acc[i][nf], 0, 0, 0);
        __builtin_amdgcn_s_setprio(0);
    }

    // epilogue: kz0 -> stage (w,b); kz>=1 -> part[(kz-1)][j*128+m][h] = fp16(acc*w)
#pragma unroll
    for (int mf = 0; mf < 4; mf++) {
#pragma unroll
        for (int r = 0; r < 4; r++) {
            const int m_local = wm + mf * 16 + fq * 4 + r;
            if (tile_m + m_local < cnt) {
                const float w = wgt[m_local], b = bia[m_local];
                __half* sp;
                if (kz == 0) {
                    sp = (slt[m_local] ? stage1 : stage0) + (size_t)toks[m_local] * HDIM;
                } else {
                    sp = part + ((size_t)(kz - 1) * LROWS + blockIdx.x * TMT + m_local) * HDIM;
                }
#pragma unroll
                for (int nf = 0; nf < 4; nf++) {
                    const int h = tn + wn + nf * 16 + fm;
                    sp[h] = __float2half(acc[mf][nf][r] * w + b);
                }
            }
        }
    }
}

// ------- combine_tail: fold the 3 K-partials into stage for leftover rows -------------
// One block per leftover row r (j = r>>7): stage_sl[tok][h] += sum_kz part[kz][r][h].
// Each (tok,slot) appears exactly once in the leftover set -> single RMW writer.
__global__ __launch_bounds__(256) void combine_tail(const int* __restrict__ lists,
                                                    const int* __restrict__ ctrl,
                                                    const int* __restrict__ tmap128,
                                                    const __half* __restrict__ part,
                                                    __half* __restrict__ stage0,
                                                    __half* __restrict__ stage1) {
    const int r = blockIdx.x;            // 0..2047
    const int ent = tmap128[r >> 7];
    if (ent < 0) return;
    const int e = ent >> 16;
    const int idx = (ent & 0xFFFF) * TMT + (r & 127);
    if (idx >= ctrl[e * 16]) return;
    const int entry = lists[e * NTOK + idx];
    const int tok = entry & 0xFFFF;
    __half* sp = ((entry >> 16) ? stage1 : stage0) + (size_t)tok * HDIM;
    const __half* pp = part + (size_t)r * HDIM;
    const int h = threadIdx.x * 4;
    union U { ushort4 v; __half x[4]; } s, p0, p1, p2, o;
    s.v  = *(const ushort4*)(sp + h);
    p0.v = *(const ushort4*)(pp + h);
    p1.v = *(const ushort4*)(pp + (size_t)LROWS * HDIM + h);
    p2.v = *(const ushort4*)(pp + (size_t)2 * LROWS * HDIM + h);
#pragma unroll
    for (int i = 0; i < 4; i++)
        o.x[i] = __float2half(__half2float(s.x[i]) + __half2float(p0.x[i]) +
                              __half2float(p1.x[i]) + __half2float(p2.x[i]));
    *(ushort4*)(sp + h) = o.v;
}

// ---------------- combine: out = stage0 + stage1 (fully coalesced) ----------------
__global__ __launch_bounds__(256) void combine(const __half* __restrict__ s0,
                                               const __half* __restrict__ s1,
                                               float* __restrict__ out) {
    const size_t idx = ((size_t)blockIdx.x * 256 + threadIdx.x) * 8;
    union { uint4 v; __half h[8]; } a, b;
    a.v = *(const uint4*)(s0 + idx);
    b.v = *(const uint4*)(s1 + idx);
    float4 o0, o1;
    o0.x = __half2float(a.h[0]) + __half2float(b.h[0]);
    o0.y = __half2float(a.h[1]) + __half2float(b.h[1]);
    o0.z = __half2float(a.h[2]) + __half2float(b.h[2]);
    o0.w = __half2float(a.h[3]) + __half2float(b.h[3]);
    o1.x = __half2float(a.h[4]) + __half2float(b.h[4]);
    o1.y = __half2float(a.h[5]) + __half2float(b.h[5]);
    o1.z = __half2float(a.h[6]) + __half2float(b.h[6]);
    o1.w = __half2float(a.h[7]) + __half2float(b.h[7]);
    *(float4*)(out + idx)     = o0;
    *(float4*)(out + idx + 4) = o1;
}

extern "C" void kernel_launch(void* const* d_in, const int* in_sizes, int n_in,
                              void* d_out, int out_size, void* d_ws, size_t ws_size,
                              hipStream_t stream) {
    const float* x  = (const float*)d_in[0];   // [4,2048,1024]
    const float* rw = (const float*)d_in[1];   // [8,1024]
    const float* ew = (const float*)d_in[2];   // [8,1024,1024]
    float* out = (float*)d_out;

    char* ws = (char*)d_ws;
    u16*    x_bf    = (u16*)ws;                          // 16 MiB
    u16*    w_bf    = (u16*)(ws + 16777216);             // 16 MiB
    __half* stage0  = (__half*)(ws + 33554432);          // 16 MiB
    __half* stage1  = (__half*)(ws + 50331648);          // 16 MiB
    float*  wt0     = (float*)(ws + 67108864);           // 32 KiB
    float*  wt1     = (float*)(ws + 67141632);           // 32 KiB
    float*  biasv   = (float*)(ws + 67174400);           // 32 KiB
    int*    sel     = (int*)(ws + 67207168);             // 32 KiB
    int*    lists   = (int*)(ws + 67239936);             // 256 KiB
    int*    ctrl    = (int*)(ws + 67502080);             // 528 B
    int*    tmap    = (int*)(ws + 67502720);             // 288 B (72 x 256-tiles)
    int*    tmap128 = (int*)(ws + 67503104);             // 64 B (16 x 128-tiles)
    __half* part    = (__half*)(ws + 67512320);          // 3 x 2048 x 1024 fp16 = 12 MiB
    // part ends at ~80.1 MiB -- within the ws >= 101,057,696 bytes proven in round 7.

    prep<<<WBLK + RBLK, 256, 0, stream>>>(x, rw, ew, x_bf, w_bf, wt0, wt1, biasv, sel, ctrl);
    build_lists<<<NTOK / 256, 256, 0, stream>>>(sel, lists, ctrl, tmap, tmap128);
    moe_gemm_fat<<<dim3(FATT, 4, 1), 512, 0, stream>>>(
        x_bf, w_bf, lists, ctrl, tmap, wt0, wt1, biasv, stage0, stage1);
    moe_gemm_thin<<<dim3(16, 8, KST), 256, 0, stream>>>(
        x_bf, w_bf, lists, ctrl, tmap128, wt0, wt1, biasv, stage0, stage1, part);
    combine_tail<<<LROWS, 256, 0, stream>>>(lists, ctrl, tmap128, part, stage0, stage1);
    combine<<<(NTOK * HDIM) / (256 * 8), 256, 0, stream>>>(stage0, stage1, out);
}